// Round 1
// baseline (1170.733 us; speedup 1.0000x reference)
//
#include <hip/hip_runtime.h>

#define NN 100000
#define NE 1600000
#define HDIM 64
#define EDIM 32
#define NTT 3
#define ETT 4
#define LEPS 1e-5f

// ---------------- edge gate weights for BOTH layers in one pass ----------------
__global__ void edge_weights_kernel(const float* __restrict__ edge_attr,
                                    const int* __restrict__ edge_type,
                                    const float* __restrict__ Wm,   // [2][4][32]
                                    const float* __restrict__ bm,   // [2][4]
                                    const float* __restrict__ emb,  // [2][4][32]
                                    float* __restrict__ w0,
                                    float* __restrict__ w1) {
    __shared__ float sWm[2 * ETT * EDIM];   // 256 floats
    __shared__ float sc[2 * ETT];
    const int tid = threadIdx.x;
    if (tid < 2 * ETT * EDIM) sWm[tid] = Wm[tid];
    __syncthreads();
    if (tid < 2 * ETT) {
        float c = bm[tid];
        #pragma unroll
        for (int k = 0; k < EDIM; k++) c += emb[tid * EDIM + k] * sWm[tid * EDIM + k];
        sc[tid] = c;
    }
    __syncthreads();
    const int e = blockIdx.x * blockDim.x + tid;
    if (e >= NE) return;
    const int et = edge_type[e];
    const float4* ea = (const float4*)(edge_attr + (size_t)e * EDIM);
    const float4* m0 = (const float4*)(sWm + et * EDIM);
    const float4* m1 = (const float4*)(sWm + (ETT + et) * EDIM);
    float d0 = sc[et];
    float d1 = sc[ETT + et];
    #pragma unroll
    for (int k = 0; k < EDIM / 4; k++) {
        const float4 v = ea[k];
        const float4 a = m0[k];
        const float4 b = m1[k];
        d0 += v.x * a.x + v.y * a.y + v.z * a.z + v.w * a.w;
        d1 += v.x * b.x + v.y * b.y + v.z * b.z + v.w * b.w;
    }
    // softplus(x) = logaddexp(x, 0) = max(x,0) + log1p(exp(-|x|))  (stable, matches jax)
    w0[e] = fmaxf(d0, 0.f) + log1pf(expf(-fabsf(d0)));
    w1[e] = fmaxf(d1, 0.f) + log1pf(expf(-fabsf(d1)));
}

// ---------------- scatter: aggr[dst] += w * (x[src] - x[dst]) ----------------
// one wave per edge; lane owns feature d.
__global__ void scatter_kernel(const float* __restrict__ x,
                               const int* __restrict__ ei,   // [2][NE] (src row then dst row)
                               const float* __restrict__ w,
                               float* __restrict__ aggr) {
    const int lane = threadIdx.x & 63;
    const int wave = (blockIdx.x * blockDim.x + threadIdx.x) >> 6;
    const int nwaves = (gridDim.x * blockDim.x) >> 6;
    for (int e = wave; e < NE; e += nwaves) {
        const int s = ei[e];
        const int t = ei[NE + e];
        const float we = w[e];
        const float v = we * (x[(size_t)s * HDIM + lane] - x[(size_t)t * HDIM + lane]);
        atomicAdd(&aggr[(size_t)t * HDIM + lane], v);
    }
}

// ---------------- node update: h = relu(aggr @ Wn[nt] + bn[nt]); LN ----------------
// one wave per node; lane owns output channel o.
__global__ void node_update_kernel(const float* __restrict__ aggr,
                                   const int* __restrict__ node_type,
                                   const float* __restrict__ Wn,  // [NTT][64][64] (this layer)
                                   const float* __restrict__ bn,  // [NTT][64]
                                   const float* __restrict__ g,   // [64]
                                   const float* __restrict__ b,   // [64]
                                   float* __restrict__ xout) {
    const int lane = threadIdx.x & 63;
    const int wib = threadIdx.x >> 6;
    const int n = blockIdx.x * (blockDim.x >> 6) + wib;
    if (n >= NN) return;
    const int nt = node_type[n];
    const float a = aggr[(size_t)n * HDIM + lane];
    const float* Wt = Wn + (size_t)nt * HDIM * HDIM;
    float h = 0.f;
    #pragma unroll
    for (int d = 0; d < HDIM; d++) {
        h += __shfl(a, d) * Wt[d * HDIM + lane];
    }
    h += bn[nt * HDIM + lane];
    h = fmaxf(h, 0.f);
    // LayerNorm across the 64 lanes
    float mu = h;
    #pragma unroll
    for (int o = 1; o < 64; o <<= 1) mu += __shfl_xor(mu, o);
    mu *= (1.f / 64.f);
    const float dh = h - mu;
    float var = dh * dh;
    #pragma unroll
    for (int o = 1; o < 64; o <<= 1) var += __shfl_xor(var, o);
    var *= (1.f / 64.f);
    const float xn = dh * rsqrtf(var + LEPS) * g[lane] + b[lane];
    xout[(size_t)n * HDIM + lane] = xn;
}

// ---------------- final FC: out = x @ fc_w^T + fc_b ----------------
__global__ void fc_kernel(const float* __restrict__ x,
                          const float* __restrict__ fc_w,  // [64][64] (o-major)
                          const float* __restrict__ fc_b,  // [64]
                          float* __restrict__ out) {
    __shared__ float sW[HDIM * HDIM];  // transposed: sW[h*64+o] = fc_w[o*64+h]
    for (int i = threadIdx.x; i < HDIM * HDIM; i += blockDim.x) {
        const int o = i >> 6, hh = i & 63;
        sW[hh * HDIM + o] = fc_w[i];
    }
    __syncthreads();
    const int lane = threadIdx.x & 63;
    const int wib = threadIdx.x >> 6;
    const int n = blockIdx.x * (blockDim.x >> 6) + wib;
    if (n >= NN) return;
    const float xv = x[(size_t)n * HDIM + lane];
    float acc = fc_b[lane];
    #pragma unroll
    for (int hh = 0; hh < HDIM; hh++) {
        acc += __shfl(xv, hh) * sW[hh * HDIM + lane];
    }
    out[(size_t)n * HDIM + lane] = acc;
}

extern "C" void kernel_launch(void* const* d_in, const int* in_sizes, int n_in,
                              void* d_out, int out_size, void* d_ws, size_t ws_size,
                              hipStream_t stream) {
    const float* x         = (const float*)d_in[0];
    const int*   ei        = (const int*)d_in[1];
    const float* edge_attr = (const float*)d_in[2];
    const int*   node_type = (const int*)d_in[3];
    const int*   edge_type = (const int*)d_in[4];
    const float* Wn        = (const float*)d_in[5];   // [2][3][64][64]
    const float* bn        = (const float*)d_in[6];   // [2][3][64]
    const float* Wm        = (const float*)d_in[7];   // [2][4][32]
    const float* bm        = (const float*)d_in[8];   // [2][4]
    const float* emb       = (const float*)d_in[9];   // [2][4][32]
    const float* ln_g      = (const float*)d_in[10];  // [2][64]
    const float* ln_b      = (const float*)d_in[11];  // [2][64]
    const float* fc_w      = (const float*)d_in[12];  // [64][64]
    const float* fc_b      = (const float*)d_in[13];  // [64]
    float* out = (float*)d_out;

    float* ws   = (float*)d_ws;
    float* w0   = ws;                                  // NE
    float* w1   = w0 + NE;                             // NE
    float* aggr = w1 + NE;                             // NN*64
    float* xbuf = aggr + (size_t)NN * HDIM;            // NN*64

    // edge gates for both layers (single edge_attr pass)
    edge_weights_kernel<<<NE / 256, 256, 0, stream>>>(edge_attr, edge_type, Wm, bm, emb, w0, w1);

    // ---- layer 0 ----
    hipMemsetAsync(aggr, 0, (size_t)NN * HDIM * sizeof(float), stream);
    scatter_kernel<<<4096, 256, 0, stream>>>(x, ei, w0, aggr);
    node_update_kernel<<<NN / 4, 256, 0, stream>>>(aggr, node_type,
                                                   Wn, bn, ln_g, ln_b, xbuf);
    // ---- layer 1 ----
    hipMemsetAsync(aggr, 0, (size_t)NN * HDIM * sizeof(float), stream);
    scatter_kernel<<<4096, 256, 0, stream>>>(xbuf, ei, w1, aggr);
    node_update_kernel<<<NN / 4, 256, 0, stream>>>(aggr, node_type,
                                                   Wn + (size_t)NTT * HDIM * HDIM,
                                                   bn + NTT * HDIM,
                                                   ln_g + HDIM, ln_b + HDIM, xbuf);
    // ---- final FC ----
    fc_kernel<<<NN / 4, 256, 0, stream>>>(xbuf, fc_w, fc_b, out);
}

// Round 2
// 981.341 us; speedup vs baseline: 1.1930x; 1.1930x over previous
//
#include <hip/hip_runtime.h>

#define NN 100000
#define NE 1600000
#define HDIM 64
#define EDIM 32
#define NTT 3
#define ETT 4
#define LEPS 1e-5f
#define SCAN_T 1024

// ------ pass 1: edge gate weights for BOTH layers + degree histogram ------
__global__ void edge_weights_kernel(const float* __restrict__ edge_attr,
                                    const int* __restrict__ ei,         // [2][NE]
                                    const int* __restrict__ edge_type,
                                    const float* __restrict__ Wm,   // [2][4][32]
                                    const float* __restrict__ bm,   // [2][4]
                                    const float* __restrict__ emb,  // [2][4][32]
                                    float* __restrict__ w0,
                                    float* __restrict__ w1,
                                    int* __restrict__ deg) {
    __shared__ float sWm[2 * ETT * EDIM];   // 256 floats
    __shared__ float sc[2 * ETT];
    const int tid = threadIdx.x;
    if (tid < 2 * ETT * EDIM) sWm[tid] = Wm[tid];
    __syncthreads();
    if (tid < 2 * ETT) {
        float c = bm[tid];
        #pragma unroll
        for (int k = 0; k < EDIM; k++) c += emb[tid * EDIM + k] * sWm[tid * EDIM + k];
        sc[tid] = c;
    }
    __syncthreads();
    const int e = blockIdx.x * blockDim.x + tid;
    if (e >= NE) return;
    const int et = edge_type[e];
    const float4* ea = (const float4*)(edge_attr + (size_t)e * EDIM);
    const float4* m0 = (const float4*)(sWm + et * EDIM);
    const float4* m1 = (const float4*)(sWm + (ETT + et) * EDIM);
    float d0 = sc[et];
    float d1 = sc[ETT + et];
    #pragma unroll
    for (int k = 0; k < EDIM / 4; k++) {
        const float4 v = ea[k];
        const float4 a = m0[k];
        const float4 b = m1[k];
        d0 += v.x * a.x + v.y * a.y + v.z * a.z + v.w * a.w;
        d1 += v.x * b.x + v.y * b.y + v.z * b.z + v.w * b.w;
    }
    // softplus(x) = max(x,0) + log1p(exp(-|x|))  (stable, matches jax)
    w0[e] = fmaxf(d0, 0.f) + log1pf(expf(-fabsf(d0)));
    w1[e] = fmaxf(d1, 0.f) + log1pf(expf(-fabsf(d1)));
    atomicAdd(&deg[ei[NE + e]], 1);
}

// ------ pass 2: exclusive scan of degrees (single block) ------
__global__ void scan_kernel(const int* __restrict__ deg,
                            int* __restrict__ off,
                            int* __restrict__ cursor) {
    __shared__ int part[SCAN_T];
    const int tid = threadIdx.x;
    const int chunk = (NN + SCAN_T - 1) / SCAN_T;   // 98
    const int lo = tid * chunk;
    const int hi = min(lo + chunk, NN);
    int s = 0;
    for (int i = lo; i < hi; i++) s += deg[i];
    part[tid] = s;
    __syncthreads();
    for (int d = 1; d < SCAN_T; d <<= 1) {
        int v = (tid >= d) ? part[tid - d] : 0;
        __syncthreads();
        part[tid] += v;
        __syncthreads();
    }
    int run = (tid == 0) ? 0 : part[tid - 1];
    for (int i = lo; i < hi; i++) {
        off[i] = run;
        cursor[i] = run;
        run += deg[i];
    }
    if (tid == SCAN_T - 1) off[NN] = NE;
}

// ------ pass 3: place edges into CSR order ------
__global__ void build_kernel(const int* __restrict__ ei,
                             const float* __restrict__ w0,
                             const float* __restrict__ w1,
                             int* __restrict__ cursor,
                             int* __restrict__ src_s,
                             float* __restrict__ w0s,
                             float* __restrict__ w1s) {
    const int e = blockIdx.x * blockDim.x + threadIdx.x;
    if (e >= NE) return;
    const int t = ei[NE + e];
    const int pos = atomicAdd(&cursor[t], 1);
    src_s[pos] = ei[e];
    w0s[pos] = w0[e];
    w1s[pos] = w1[e];
}

// ------ fused layer: gather + per-type matvec + ReLU + LayerNorm (+ optional FC) ------
// one wave per node, lane owns feature; weights for all node types in LDS.
__global__ __launch_bounds__(512)
void gnn_layer_kernel(const float* __restrict__ xin,
                      const int* __restrict__ off,
                      const int* __restrict__ src_s,
                      const float* __restrict__ wsort,
                      const int* __restrict__ node_type,
                      const float* __restrict__ Wn,   // [3][64][64] this layer
                      const float* __restrict__ bn,   // [3][64]
                      const float* __restrict__ g,    // [64]
                      const float* __restrict__ b,    // [64]
                      const float* __restrict__ fc_w, // [64][64] or unused
                      const float* __restrict__ fc_b, // [64] or unused
                      float* __restrict__ xout,
                      int fuse_fc) {
    extern __shared__ float smem[];
    float* sW = smem;                 // 3*4096
    float* sFC = smem + NTT * HDIM * HDIM;  // 4096 (only if fuse_fc)
    for (int i = threadIdx.x; i < NTT * HDIM * HDIM; i += 512) sW[i] = Wn[i];
    if (fuse_fc) {
        for (int i = threadIdx.x; i < HDIM * HDIM; i += 512) {
            const int o = i >> 6, hh = i & 63;
            sFC[hh * HDIM + o] = fc_w[i];   // transpose: sFC[h][o]
        }
    }
    __syncthreads();

    const int lane = threadIdx.x & 63;
    const int wib = threadIdx.x >> 6;
    const int n = blockIdx.x * 8 + wib;
    if (n >= NN) return;

    const int lo = off[n], hi = off[n + 1];
    float acc = 0.f, sumw = 0.f;
    int i = lo;
    for (; i + 4 <= hi; i += 4) {
        const int s0 = src_s[i], s1 = src_s[i + 1], s2 = src_s[i + 2], s3 = src_s[i + 3];
        const float a0 = wsort[i], a1 = wsort[i + 1], a2 = wsort[i + 2], a3 = wsort[i + 3];
        acc += a0 * xin[(size_t)s0 * HDIM + lane];
        acc += a1 * xin[(size_t)s1 * HDIM + lane];
        acc += a2 * xin[(size_t)s2 * HDIM + lane];
        acc += a3 * xin[(size_t)s3 * HDIM + lane];
        sumw += a0 + a1 + a2 + a3;
    }
    for (; i < hi; i++) {
        const int s = src_s[i];
        const float a = wsort[i];
        acc += a * xin[(size_t)s * HDIM + lane];
        sumw += a;
    }
    acc -= sumw * xin[(size_t)n * HDIM + lane];

    // per-node-type matvec: h[o] = sum_d acc[d] * Wn[nt][d][o] + bn[nt][o]
    const int nt = node_type[n];
    const float* Wt = sW + nt * HDIM * HDIM;
    float h = bn[nt * HDIM + lane];
    #pragma unroll
    for (int d = 0; d < HDIM; d++) h += __shfl(acc, d) * Wt[d * HDIM + lane];
    h = fmaxf(h, 0.f);

    // LayerNorm across 64 lanes
    float mu = h;
    #pragma unroll
    for (int o = 1; o < 64; o <<= 1) mu += __shfl_xor(mu, o);
    mu *= (1.f / 64.f);
    const float dh = h - mu;
    float var = dh * dh;
    #pragma unroll
    for (int o = 1; o < 64; o <<= 1) var += __shfl_xor(var, o);
    var *= (1.f / 64.f);
    const float xn = dh * rsqrtf(var + LEPS) * g[lane] + b[lane];

    if (!fuse_fc) {
        xout[(size_t)n * HDIM + lane] = xn;
    } else {
        float oacc = fc_b[lane];
        #pragma unroll
        for (int hh = 0; hh < HDIM; hh++) oacc += __shfl(xn, hh) * sFC[hh * HDIM + lane];
        xout[(size_t)n * HDIM + lane] = oacc;
    }
}

extern "C" void kernel_launch(void* const* d_in, const int* in_sizes, int n_in,
                              void* d_out, int out_size, void* d_ws, size_t ws_size,
                              hipStream_t stream) {
    const float* x         = (const float*)d_in[0];
    const int*   ei        = (const int*)d_in[1];
    const float* edge_attr = (const float*)d_in[2];
    const int*   node_type = (const int*)d_in[3];
    const int*   edge_type = (const int*)d_in[4];
    const float* Wn        = (const float*)d_in[5];   // [2][3][64][64]
    const float* bn        = (const float*)d_in[6];   // [2][3][64]
    const float* Wm        = (const float*)d_in[7];   // [2][4][32]
    const float* bm        = (const float*)d_in[8];   // [2][4]
    const float* emb       = (const float*)d_in[9];   // [2][4][32]
    const float* ln_g      = (const float*)d_in[10];  // [2][64]
    const float* ln_b      = (const float*)d_in[11];  // [2][64]
    const float* fc_w      = (const float*)d_in[12];  // [64][64]
    const float* fc_b      = (const float*)d_in[13];  // [64]
    float* out = (float*)d_out;

    float* ws    = (float*)d_ws;
    float* w0    = ws;                       // NE
    float* w1    = w0 + NE;                  // NE
    float* w0s   = w1 + NE;                  // NE
    float* w1s   = w0s + NE;                 // NE
    int*   src_s = (int*)(w1s + NE);         // NE
    int*   deg   = src_s + NE;               // NN
    int*   off   = deg + NN;                 // NN+1
    int*   curs  = off + NN + 1;             // NN
    float* xbuf  = (float*)(curs + NN);      // NN*64
    // total: 5*NE + 3*NN + 1 + NN*64 floats ≈ 58.8 MB

    hipMemsetAsync(deg, 0, NN * sizeof(int), stream);
    edge_weights_kernel<<<NE / 256, 256, 0, stream>>>(edge_attr, ei, edge_type,
                                                      Wm, bm, emb, w0, w1, deg);
    scan_kernel<<<1, SCAN_T, 0, stream>>>(deg, off, curs);
    build_kernel<<<NE / 256, 256, 0, stream>>>(ei, w0, w1, curs, src_s, w0s, w1s);

    const int grid = NN / 8;  // 12500 blocks x 8 waves
    // layer 0: gather + matvec + LN -> xbuf
    gnn_layer_kernel<<<grid, 512, NTT * HDIM * HDIM * sizeof(float), stream>>>(
        x, off, src_s, w0s, node_type, Wn, bn, ln_g, ln_b,
        nullptr, nullptr, xbuf, 0);
    // layer 1: gather + matvec + LN + FC -> out
    gnn_layer_kernel<<<grid, 512, (NTT + 1) * HDIM * HDIM * sizeof(float), stream>>>(
        xbuf, off, src_s, w1s, node_type,
        Wn + (size_t)NTT * HDIM * HDIM, bn + NTT * HDIM,
        ln_g + HDIM, ln_b + HDIM, fc_w, fc_b, out, 1);
}

// Round 3
// 629.006 us; speedup vs baseline: 1.8612x; 1.5601x over previous
//
#include <hip/hip_runtime.h>

#define NN 100000
#define NE 1600000
#define HDIM 64
#define EDIM 32
#define NTT 3
#define ETT 4
#define NTILES 6250
#define LEPS 1e-5f
#define SCAN_T 1024

typedef _Float16 half4v __attribute__((ext_vector_type(4)));
typedef _Float16 half8v __attribute__((ext_vector_type(8)));
typedef float f32x4 __attribute__((ext_vector_type(4)));

// ---- K0: prep weights: Wp[l][t][o][d] = f16(Wn[l][t][d][o]); fcp = f16(fc_w) ----
__global__ void prep_kernel(const float* __restrict__ Wn, const float* __restrict__ fc_w,
                            _Float16* __restrict__ Wp, _Float16* __restrict__ fcp) {
    const int i = blockIdx.x * blockDim.x + threadIdx.x;
    if (i < 6 * HDIM * HDIM) {
        const int lt = i >> 12;          // [l*3+t]
        const int o = (i >> 6) & 63;
        const int d = i & 63;
        Wp[i] = (_Float16)Wn[((size_t)lt * 64 + d) * 64 + o];
    } else if (i < 6 * HDIM * HDIM + HDIM * HDIM) {
        const int j = i - 6 * HDIM * HDIM;
        fcp[j] = (_Float16)fc_w[j];      // fc_w already [o][h] = B[k=h][col=o] o-major
    }
}

// ---- K1: edge gates for both layers + degree histogram ----
__global__ void edge_weights_kernel(const float* __restrict__ edge_attr,
                                    const int* __restrict__ ei,
                                    const int* __restrict__ edge_type,
                                    const float* __restrict__ Wm,
                                    const float* __restrict__ bm,
                                    const float* __restrict__ emb,
                                    float* __restrict__ w0,
                                    float* __restrict__ w1,
                                    int* __restrict__ deg) {
    __shared__ float sWm[2 * ETT * EDIM];
    __shared__ float sc[2 * ETT];
    const int tid = threadIdx.x;
    if (tid < 2 * ETT * EDIM) sWm[tid] = Wm[tid];
    __syncthreads();
    if (tid < 2 * ETT) {
        float c = bm[tid];
        #pragma unroll
        for (int k = 0; k < EDIM; k++) c += emb[tid * EDIM + k] * sWm[tid * EDIM + k];
        sc[tid] = c;
    }
    __syncthreads();
    const int e = blockIdx.x * blockDim.x + tid;
    if (e >= NE) return;
    const int et = edge_type[e];
    const float4* ea = (const float4*)(edge_attr + (size_t)e * EDIM);
    const float4* m0 = (const float4*)(sWm + et * EDIM);
    const float4* m1 = (const float4*)(sWm + (ETT + et) * EDIM);
    float d0 = sc[et];
    float d1 = sc[ETT + et];
    #pragma unroll
    for (int k = 0; k < EDIM / 4; k++) {
        const float4 v = ea[k];
        const float4 a = m0[k];
        const float4 b = m1[k];
        d0 += v.x * a.x + v.y * a.y + v.z * a.z + v.w * a.w;
        d1 += v.x * b.x + v.y * b.y + v.z * b.z + v.w * b.w;
    }
    w0[e] = fmaxf(d0, 0.f) + log1pf(expf(-fabsf(d0)));
    w1[e] = fmaxf(d1, 0.f) + log1pf(expf(-fabsf(d1)));
    atomicAdd(&deg[ei[NE + e]], 1);
}

// ---- K2: exclusive scan of degrees (single block) ----
__global__ void scan_kernel(const int* __restrict__ deg,
                            int* __restrict__ off,
                            int* __restrict__ cursor) {
    __shared__ int part[SCAN_T];
    const int tid = threadIdx.x;
    const int chunk = (NN + SCAN_T - 1) / SCAN_T;
    const int lo = tid * chunk;
    const int hi = min(lo + chunk, NN);
    int s = 0;
    for (int i = lo; i < hi; i++) s += deg[i];
    part[tid] = s;
    __syncthreads();
    for (int d = 1; d < SCAN_T; d <<= 1) {
        int v = (tid >= d) ? part[tid - d] : 0;
        __syncthreads();
        part[tid] += v;
        __syncthreads();
    }
    int run = (tid == 0) ? 0 : part[tid - 1];
    for (int i = lo; i < hi; i++) {
        off[i] = run;
        cursor[i] = run;
        run += deg[i];
    }
    if (tid == SCAN_T - 1) off[NN] = NE;
}

// ---- K3: x -> fp16 ----
__global__ void xcvt_kernel(const float* __restrict__ x, _Float16* __restrict__ xs) {
    const int i = blockIdx.x * blockDim.x + threadIdx.x;   // thread per 4 elems
    const float4 v = ((const float4*)x)[i];
    half4v o = { (_Float16)v.x, (_Float16)v.y, (_Float16)v.z, (_Float16)v.w };
    ((half4v*)xs)[i] = o;
}

// ---- K4: place edges into CSR order, packed {w, src} ----
__global__ void build_kernel(const int* __restrict__ ei,
                             const float* __restrict__ w0,
                             const float* __restrict__ w1,
                             int* __restrict__ cursor,
                             int2* __restrict__ ew0,
                             int2* __restrict__ ew1) {
    const int e = blockIdx.x * blockDim.x + threadIdx.x;
    if (e >= NE) return;
    const int t = ei[NE + e];
    const int s = ei[e];
    const int pos = atomicAdd(&cursor[t], 1);
    ew0[pos] = make_int2(__float_as_int(w0[e]), s);
    ew1[pos] = make_int2(__float_as_int(w1[e]), s);
}

// ---- K5/K7: gather: aggr[p] = sum w*x[src] - (sum w)*x[p]   (fp16 in/out, fp32 accum) ----
// wave per node; 4 edge-groups x 16 lanes; lane covers 4 features.
__global__ __launch_bounds__(512) void gather_kernel(const _Float16* __restrict__ xs,
                                                     const int2* __restrict__ ew,
                                                     const int* __restrict__ off,
                                                     _Float16* __restrict__ aggr) {
    const int lane = threadIdx.x & 63;
    const int wid = threadIdx.x >> 6;
    const int p = blockIdx.x * 8 + wid;            // grid covers exactly NN
    const int g = lane >> 4;
    const int fl = lane & 15;
    const int lo = off[p], hi = off[p + 1];
    float a0 = 0.f, a1 = 0.f, a2 = 0.f, a3 = 0.f, sw = 0.f;
    for (int base = lo; base < hi; base += 4) {
        const int i = base + g;
        if (i < hi) {
            const int2 e = ew[i];
            const float w = __int_as_float(e.x);
            const half4v xv = *(const half4v*)(xs + (size_t)e.y * HDIM + fl * 4);
            a0 += w * (float)xv[0];
            a1 += w * (float)xv[1];
            a2 += w * (float)xv[2];
            a3 += w * (float)xv[3];
            sw += w;
        }
    }
    // combine the 4 edge-groups (xor 16 then 32)
    a0 += __shfl_xor(a0, 16); a1 += __shfl_xor(a1, 16);
    a2 += __shfl_xor(a2, 16); a3 += __shfl_xor(a3, 16);
    sw += __shfl_xor(sw, 16);
    a0 += __shfl_xor(a0, 32); a1 += __shfl_xor(a1, 32);
    a2 += __shfl_xor(a2, 32); a3 += __shfl_xor(a3, 32);
    sw += __shfl_xor(sw, 32);
    const half4v xt = *(const half4v*)(xs + (size_t)p * HDIM + fl * 4);
    a0 -= sw * (float)xt[0];
    a1 -= sw * (float)xt[1];
    a2 -= sw * (float)xt[2];
    a3 -= sw * (float)xt[3];
    if (g == 0) {
        half4v o = { (_Float16)a0, (_Float16)a1, (_Float16)a2, (_Float16)a3 };
        *(half4v*)(aggr + (size_t)p * HDIM + fl * 4) = o;
    }
}

// ---- K6/K8: update: h = relu(aggr @ Wn[nt] + bn[nt]); LN; [FC] ----
// wave per 16-node tile; MFMA for all 3 types + per-row select.
template<int FUSE>
__global__ __launch_bounds__(256) void update_kernel(const _Float16* __restrict__ aggr,
                                                     const int* __restrict__ ntype,
                                                     const _Float16* __restrict__ Wp,  // [3][64][64] o-major
                                                     const float* __restrict__ bnp,   // [3][64]
                                                     const float* __restrict__ lng,
                                                     const float* __restrict__ lnb,
                                                     const _Float16* __restrict__ fcp, // [64][64]
                                                     const float* __restrict__ fcb,
                                                     _Float16* __restrict__ xout,
                                                     float* __restrict__ fout) {
    __shared__ float scst[320];                 // bn[192] | g[64] | b[64]
    __shared__ f32x4 sraw[4 * 4608 / 16];       // 4608 B per wave scratch
    for (int i = threadIdx.x; i < 320; i += 256)
        scst[i] = (i < 192) ? bnp[i] : ((i < 256) ? lng[i - 192] : lnb[i - 256]);
    __syncthreads();

    const int wid = threadIdx.x >> 6;
    const int lane = threadIdx.x & 63;
    const int tile = blockIdx.x * 4 + wid;
    if (tile >= NTILES) return;
    const int fl = lane & 15;
    const int gq = lane >> 4;
    const size_t R = (size_t)tile * 16;

    const half8v A0 = *(const half8v*)(aggr + (R + fl) * HDIM + gq * 8);
    const half8v A1 = *(const half8v*)(aggr + (R + fl) * HDIM + 32 + gq * 8);
    int nt[4];
    #pragma unroll
    for (int r = 0; r < 4; r++) nt[r] = ntype[R + gq * 4 + r];

    float h[4][4];
    #pragma unroll
    for (int ob = 0; ob < 4; ob++) {
        const int col = ob * 16 + fl;
        f32x4 c[3];
        #pragma unroll
        for (int t = 0; t < 3; t++) {
            const half8v B0 = *(const half8v*)(Wp + t * 4096 + col * 64 + gq * 8);
            const half8v B1 = *(const half8v*)(Wp + t * 4096 + col * 64 + 32 + gq * 8);
            f32x4 z = { 0.f, 0.f, 0.f, 0.f };
            z = __builtin_amdgcn_mfma_f32_16x16x32_f16(A0, B0, z, 0, 0, 0);
            z = __builtin_amdgcn_mfma_f32_16x16x32_f16(A1, B1, z, 0, 0, 0);
            c[t] = z;
        }
        #pragma unroll
        for (int r = 0; r < 4; r++) {
            float v = (nt[r] == 0) ? c[0][r] : ((nt[r] == 1) ? c[1][r] : c[2][r]);
            v += scst[nt[r] * 64 + col];
            h[ob][r] = fmaxf(v, 0.f);
        }
    }

    // LayerNorm per row (row = gq*4+r, its 64 cols live in the 16 lanes of this gq group)
    float mu[4], rs[4];
    #pragma unroll
    for (int r = 0; r < 4; r++) {
        float m = h[0][r] + h[1][r] + h[2][r] + h[3][r];
        m += __shfl_xor(m, 1); m += __shfl_xor(m, 2);
        m += __shfl_xor(m, 4); m += __shfl_xor(m, 8);
        mu[r] = m * (1.f / 64.f);
        const float d0 = h[0][r] - mu[r], d1 = h[1][r] - mu[r];
        const float d2 = h[2][r] - mu[r], d3 = h[3][r] - mu[r];
        float v = d0 * d0 + d1 * d1 + d2 * d2 + d3 * d3;
        v += __shfl_xor(v, 1); v += __shfl_xor(v, 2);
        v += __shfl_xor(v, 4); v += __shfl_xor(v, 8);
        rs[r] = rsqrtf(v * (1.f / 64.f) + LEPS);
    }

    _Float16* wb = (_Float16*)sraw + (size_t)wid * 2304;   // [16][72] f16 view
    #pragma unroll
    for (int ob = 0; ob < 4; ob++) {
        const int col = ob * 16 + fl;
        const float gg = scst[192 + col], bb = scst[256 + col];
        #pragma unroll
        for (int r = 0; r < 4; r++) {
            const float xn = (h[ob][r] - mu[r]) * rs[r] * gg + bb;
            wb[(gq * 4 + r) * 72 + col] = (_Float16)xn;
        }
    }
    __threadfence_block();

    if (!FUSE) {
        // coalesced fp16 write via LDS transpose: lane -> row=lane>>2, 16 cols
        const int rr = lane >> 2, cg = lane & 3;
        const half8v o0 = *(const half8v*)(wb + rr * 72 + cg * 16);
        const half8v o1 = *(const half8v*)(wb + rr * 72 + cg * 16 + 8);
        *(half8v*)(xout + (R + rr) * HDIM + cg * 16) = o0;
        *(half8v*)(xout + (R + rr) * HDIM + cg * 16 + 8) = o1;
    } else {
        // FC GEMM: read xn back in A-frag layout
        const half8v FA0 = *(const half8v*)(wb + fl * 72 + gq * 8);
        const half8v FA1 = *(const half8v*)(wb + fl * 72 + 32 + gq * 8);
        float fo[4][4];
        #pragma unroll
        for (int ob = 0; ob < 4; ob++) {
            const int col = ob * 16 + fl;
            const half8v FB0 = *(const half8v*)(fcp + col * 64 + gq * 8);
            const half8v FB1 = *(const half8v*)(fcp + col * 64 + 32 + gq * 8);
            f32x4 z = { 0.f, 0.f, 0.f, 0.f };
            z = __builtin_amdgcn_mfma_f32_16x16x32_f16(FA0, FB0, z, 0, 0, 0);
            z = __builtin_amdgcn_mfma_f32_16x16x32_f16(FA1, FB1, z, 0, 0, 0);
            const float fb = fcb[col];
            #pragma unroll
            for (int r = 0; r < 4; r++) fo[ob][r] = z[r] + fb;
        }
        __threadfence_block();
        float* fb32 = (float*)((char*)sraw + (size_t)wid * 4608);  // [16][68] f32 view
        #pragma unroll
        for (int ob = 0; ob < 4; ob++) {
            const int col = ob * 16 + fl;
            #pragma unroll
            for (int r = 0; r < 4; r++) fb32[(gq * 4 + r) * 68 + col] = fo[ob][r];
        }
        __threadfence_block();
        #pragma unroll
        for (int rr = 0; rr < 16; rr++)
            fout[(R + rr) * HDIM + lane] = fb32[rr * 68 + lane];
    }
}

extern "C" void kernel_launch(void* const* d_in, const int* in_sizes, int n_in,
                              void* d_out, int out_size, void* d_ws, size_t ws_size,
                              hipStream_t stream) {
    const float* x         = (const float*)d_in[0];
    const int*   ei        = (const int*)d_in[1];
    const float* edge_attr = (const float*)d_in[2];
    const int*   node_type = (const int*)d_in[3];
    const int*   edge_type = (const int*)d_in[4];
    const float* Wn        = (const float*)d_in[5];
    const float* bn        = (const float*)d_in[6];
    const float* Wm        = (const float*)d_in[7];
    const float* bm        = (const float*)d_in[8];
    const float* emb       = (const float*)d_in[9];
    const float* ln_g      = (const float*)d_in[10];
    const float* ln_b      = (const float*)d_in[11];
    const float* fc_w      = (const float*)d_in[12];
    const float* fc_b      = (const float*)d_in[13];
    float* out = (float*)d_out;

    char* W = (char*)d_ws;
    int2*      ew0  = (int2*)W;                               // 12.8e6 B
    int2*      ew1  = (int2*)(W + 12800000);                  // 12.8e6 B
    char*      reg  = W + 25600000;                           // 12.82e6 B region
    float*     w0   = (float*)reg;                            // 6.4e6 B
    float*     w1   = (float*)(reg + 6410000);                // 6.4e6 B
    _Float16*  aggr = (_Float16*)reg;                         // reuses region after build
    char*      p2   = reg + 12820000;
    _Float16*  xs   = (_Float16*)p2;                          // 12.8e6 B
    _Float16*  x1s  = (_Float16*)(p2 + 12800000);             // 12.8e6 B
    char*      p3   = p2 + 25600000;
    _Float16*  Wp   = (_Float16*)p3;                          // 49152 B
    _Float16*  fcp  = (_Float16*)(p3 + 49152);                // 8192 B
    int*       deg  = (int*)(p3 + 49152 + 8192);
    int*       off  = deg + NN;
    int*       curs = off + NN + 16;

    prep_kernel<<<112, 256, 0, stream>>>(Wn, fc_w, Wp, fcp);
    hipMemsetAsync(deg, 0, NN * sizeof(int), stream);
    edge_weights_kernel<<<NE / 256, 256, 0, stream>>>(edge_attr, ei, edge_type,
                                                      Wm, bm, emb, w0, w1, deg);
    scan_kernel<<<1, SCAN_T, 0, stream>>>(deg, off, curs);
    xcvt_kernel<<<6250, 256, 0, stream>>>(x, xs);
    build_kernel<<<NE / 256, 256, 0, stream>>>(ei, w0, w1, curs, ew0, ew1);

    // layer 0
    gather_kernel<<<NN / 8, 512, 0, stream>>>(xs, ew0, off, aggr);
    update_kernel<0><<<(NTILES + 3) / 4, 256, 0, stream>>>(aggr, node_type,
        Wp, bn, ln_g, ln_b, fcp, fc_b, x1s, nullptr);
    // layer 1 (+FC)
    gather_kernel<<<NN / 8, 512, 0, stream>>>(x1s, ew1, off, aggr);
    update_kernel<1><<<(NTILES + 3) / 4, 256, 0, stream>>>(aggr, node_type,
        Wp + 3 * 4096, bn + NTT * HDIM, ln_g + HDIM, ln_b + HDIM, fcp, fc_b, nullptr, out);
}

// Round 4
// 415.370 us; speedup vs baseline: 2.8185x; 1.5143x over previous
//
#include <hip/hip_runtime.h>

#define NN 100000
#define NE 1600000
#define HDIM 64
#define EDIM 32
#define NTT 3
#define ETT 4
#define NTILES 6250
#define LEPS 1e-5f
#define CHUNK 1024
#define NBLK 98   // ceil(NN / CHUNK)

typedef _Float16 half4v __attribute__((ext_vector_type(4)));
typedef _Float16 half8v __attribute__((ext_vector_type(8)));
typedef float f32x4 __attribute__((ext_vector_type(4)));

// ---- K0: prep weights: Wp[l][t][o][d] = f16(Wn[l][t][d][o]); fcp = f16(fc_w) ----
__global__ void prep_kernel(const float* __restrict__ Wn, const float* __restrict__ fc_w,
                            _Float16* __restrict__ Wp, _Float16* __restrict__ fcp) {
    const int i = blockIdx.x * blockDim.x + threadIdx.x;
    if (i < 6 * HDIM * HDIM) {
        const int lt = i >> 12;          // [l*3+t]
        const int o = (i >> 6) & 63;
        const int d = i & 63;
        Wp[i] = (_Float16)Wn[((size_t)lt * 64 + d) * 64 + o];
    } else if (i < 6 * HDIM * HDIM + HDIM * HDIM) {
        const int j = i - 6 * HDIM * HDIM;
        fcp[j] = (_Float16)fc_w[j];      // fc_w already [o][h]
    }
}

// ---- K1: edge gates for both layers + degree histogram ----
__global__ void edge_weights_kernel(const float* __restrict__ edge_attr,
                                    const int* __restrict__ ei,
                                    const int* __restrict__ edge_type,
                                    const float* __restrict__ Wm,
                                    const float* __restrict__ bm,
                                    const float* __restrict__ emb,
                                    float* __restrict__ w0,
                                    float* __restrict__ w1,
                                    int* __restrict__ deg) {
    __shared__ float sWm[2 * ETT * EDIM];
    __shared__ float sc[2 * ETT];
    const int tid = threadIdx.x;
    if (tid < 2 * ETT * EDIM) sWm[tid] = Wm[tid];
    __syncthreads();
    if (tid < 2 * ETT) {
        float c = bm[tid];
        #pragma unroll
        for (int k = 0; k < EDIM; k++) c += emb[tid * EDIM + k] * sWm[tid * EDIM + k];
        sc[tid] = c;
    }
    __syncthreads();
    const int e = blockIdx.x * blockDim.x + tid;
    if (e >= NE) return;
    const int et = edge_type[e];
    const float4* ea = (const float4*)(edge_attr + (size_t)e * EDIM);
    const float4* m0 = (const float4*)(sWm + et * EDIM);
    const float4* m1 = (const float4*)(sWm + (ETT + et) * EDIM);
    float d0 = sc[et];
    float d1 = sc[ETT + et];
    #pragma unroll
    for (int k = 0; k < EDIM / 4; k++) {
        const float4 v = ea[k];
        const float4 a = m0[k];
        const float4 b = m1[k];
        d0 += v.x * a.x + v.y * a.y + v.z * a.z + v.w * a.w;
        d1 += v.x * b.x + v.y * b.y + v.z * b.z + v.w * b.w;
    }
    w0[e] = fmaxf(d0, 0.f) + log1pf(expf(-fabsf(d0)));
    w1[e] = fmaxf(d1, 0.f) + log1pf(expf(-fabsf(d1)));
    atomicAdd(&deg[ei[NE + e]], 1);
}

// ---- K2a: per-chunk sums ----
__global__ __launch_bounds__(256) void partial_kernel(const int* __restrict__ deg,
                                                      int* __restrict__ bsum) {
    __shared__ int red[256];
    const int b = blockIdx.x, t = threadIdx.x;
    const int base = b * CHUNK + t * 4;
    int s = 0;
    #pragma unroll
    for (int k = 0; k < 4; k++) { const int i = base + k; if (i < NN) s += deg[i]; }
    red[t] = s;
    __syncthreads();
    for (int d = 128; d > 0; d >>= 1) {
        if (t < d) red[t] += red[t + d];
        __syncthreads();
    }
    if (t == 0) bsum[b] = red[0];
}

// ---- K2b: exclusive scan of the 98 chunk sums (1 tiny block) ----
__global__ void bscan_kernel(const int* __restrict__ bsum, int* __restrict__ boff) {
    __shared__ int v[128];
    const int t = threadIdx.x;
    v[t] = (t < NBLK) ? bsum[t] : 0;
    __syncthreads();
    for (int d = 1; d < 128; d <<= 1) {
        const int x = (t >= d) ? v[t - d] : 0;
        __syncthreads();
        v[t] += x;
        __syncthreads();
    }
    boff[t] = (t == 0) ? 0 : v[t - 1];
}

// ---- K2c: intra-chunk exclusive scan -> off, cursor ----
__global__ __launch_bounds__(256) void offsets_kernel(const int* __restrict__ deg,
                                                      const int* __restrict__ boff,
                                                      int* __restrict__ off,
                                                      int* __restrict__ cursor) {
    __shared__ int red[256];
    const int b = blockIdx.x, t = threadIdx.x;
    const int base = b * CHUNK + t * 4;
    int d4[4];
    #pragma unroll
    for (int k = 0; k < 4; k++) d4[k] = (base + k < NN) ? deg[base + k] : 0;
    const int s = d4[0] + d4[1] + d4[2] + d4[3];
    red[t] = s;
    __syncthreads();
    for (int d = 1; d < 256; d <<= 1) {
        const int x = (t >= d) ? red[t - d] : 0;
        __syncthreads();
        red[t] += x;
        __syncthreads();
    }
    int run = boff[b] + ((t == 0) ? 0 : red[t - 1]);
    #pragma unroll
    for (int k = 0; k < 4; k++) {
        if (base + k < NN) {
            off[base + k] = run;
            cursor[base + k] = run;
            run += d4[k];
        }
    }
    if (b == NBLK - 1 && t == 255) off[NN] = NE;
}

// ---- K3: x -> fp16 ----
__global__ void xcvt_kernel(const float* __restrict__ x, _Float16* __restrict__ xs) {
    const int i = blockIdx.x * blockDim.x + threadIdx.x;
    const float4 v = ((const float4*)x)[i];
    half4v o = { (_Float16)v.x, (_Float16)v.y, (_Float16)v.z, (_Float16)v.w };
    ((half4v*)xs)[i] = o;
}

// ---- K4: place edges into CSR order, packed {w, src} ----
__global__ void build_kernel(const int* __restrict__ ei,
                             const float* __restrict__ w0,
                             const float* __restrict__ w1,
                             int* __restrict__ cursor,
                             int2* __restrict__ ew0,
                             int2* __restrict__ ew1) {
    const int e = blockIdx.x * blockDim.x + threadIdx.x;
    if (e >= NE) return;
    const int t = ei[NE + e];
    const int s = ei[e];
    const int pos = atomicAdd(&cursor[t], 1);
    ew0[pos] = make_int2(__float_as_int(w0[e]), s);
    ew1[pos] = make_int2(__float_as_int(w1[e]), s);
}

// ---- K5/K7: gather: aggr[p] = sum w*x[src] - (sum w)*x[p] ----
__global__ __launch_bounds__(512) void gather_kernel(const _Float16* __restrict__ xs,
                                                     const int2* __restrict__ ew,
                                                     const int* __restrict__ off,
                                                     _Float16* __restrict__ aggr) {
    const int lane = threadIdx.x & 63;
    const int wid = threadIdx.x >> 6;
    const int p = blockIdx.x * 8 + wid;
    const int g = lane >> 4;
    const int fl = lane & 15;
    const int lo = off[p], hi = off[p + 1];
    float a0 = 0.f, a1 = 0.f, a2 = 0.f, a3 = 0.f, sw = 0.f;
    for (int base = lo; base < hi; base += 4) {
        const int i = base + g;
        if (i < hi) {
            const int2 e = ew[i];
            const float w = __int_as_float(e.x);
            const half4v xv = *(const half4v*)(xs + (size_t)e.y * HDIM + fl * 4);
            a0 += w * (float)xv[0];
            a1 += w * (float)xv[1];
            a2 += w * (float)xv[2];
            a3 += w * (float)xv[3];
            sw += w;
        }
    }
    a0 += __shfl_xor(a0, 16); a1 += __shfl_xor(a1, 16);
    a2 += __shfl_xor(a2, 16); a3 += __shfl_xor(a3, 16);
    sw += __shfl_xor(sw, 16);
    a0 += __shfl_xor(a0, 32); a1 += __shfl_xor(a1, 32);
    a2 += __shfl_xor(a2, 32); a3 += __shfl_xor(a3, 32);
    sw += __shfl_xor(sw, 32);
    const half4v xt = *(const half4v*)(xs + (size_t)p * HDIM + fl * 4);
    a0 -= sw * (float)xt[0];
    a1 -= sw * (float)xt[1];
    a2 -= sw * (float)xt[2];
    a3 -= sw * (float)xt[3];
    if (g == 0) {
        half4v o = { (_Float16)a0, (_Float16)a1, (_Float16)a2, (_Float16)a3 };
        *(half4v*)(aggr + (size_t)p * HDIM + fl * 4) = o;
    }
}

// ---- K6/K8: update: h = relu(aggr @ Wn[nt] + bn[nt]); LN; [FC] ----
template<int FUSE>
__global__ __launch_bounds__(256) void update_kernel(const _Float16* __restrict__ aggr,
                                                     const int* __restrict__ ntype,
                                                     const _Float16* __restrict__ Wp,
                                                     const float* __restrict__ bnp,
                                                     const float* __restrict__ lng,
                                                     const float* __restrict__ lnb,
                                                     const _Float16* __restrict__ fcp,
                                                     const float* __restrict__ fcb,
                                                     _Float16* __restrict__ xout,
                                                     float* __restrict__ fout) {
    __shared__ float scst[320];
    __shared__ f32x4 sraw[4 * 4608 / 16];
    for (int i = threadIdx.x; i < 320; i += 256)
        scst[i] = (i < 192) ? bnp[i] : ((i < 256) ? lng[i - 192] : lnb[i - 256]);
    __syncthreads();

    const int wid = threadIdx.x >> 6;
    const int lane = threadIdx.x & 63;
    const int tile = blockIdx.x * 4 + wid;
    if (tile >= NTILES) return;
    const int fl = lane & 15;
    const int gq = lane >> 4;
    const size_t R = (size_t)tile * 16;

    const half8v A0 = *(const half8v*)(aggr + (R + fl) * HDIM + gq * 8);
    const half8v A1 = *(const half8v*)(aggr + (R + fl) * HDIM + 32 + gq * 8);
    int nt[4];
    #pragma unroll
    for (int r = 0; r < 4; r++) nt[r] = ntype[R + gq * 4 + r];

    float h[4][4];
    #pragma unroll
    for (int ob = 0; ob < 4; ob++) {
        const int col = ob * 16 + fl;
        f32x4 c[3];
        #pragma unroll
        for (int t = 0; t < 3; t++) {
            const half8v B0 = *(const half8v*)(Wp + t * 4096 + col * 64 + gq * 8);
            const half8v B1 = *(const half8v*)(Wp + t * 4096 + col * 64 + 32 + gq * 8);
            f32x4 z = { 0.f, 0.f, 0.f, 0.f };
            z = __builtin_amdgcn_mfma_f32_16x16x32_f16(A0, B0, z, 0, 0, 0);
            z = __builtin_amdgcn_mfma_f32_16x16x32_f16(A1, B1, z, 0, 0, 0);
            c[t] = z;
        }
        #pragma unroll
        for (int r = 0; r < 4; r++) {
            float v = (nt[r] == 0) ? c[0][r] : ((nt[r] == 1) ? c[1][r] : c[2][r]);
            v += scst[nt[r] * 64 + col];
            h[ob][r] = fmaxf(v, 0.f);
        }
    }

    float mu[4], rs[4];
    #pragma unroll
    for (int r = 0; r < 4; r++) {
        float m = h[0][r] + h[1][r] + h[2][r] + h[3][r];
        m += __shfl_xor(m, 1); m += __shfl_xor(m, 2);
        m += __shfl_xor(m, 4); m += __shfl_xor(m, 8);
        mu[r] = m * (1.f / 64.f);
        const float d0 = h[0][r] - mu[r], d1 = h[1][r] - mu[r];
        const float d2 = h[2][r] - mu[r], d3 = h[3][r] - mu[r];
        float v = d0 * d0 + d1 * d1 + d2 * d2 + d3 * d3;
        v += __shfl_xor(v, 1); v += __shfl_xor(v, 2);
        v += __shfl_xor(v, 4); v += __shfl_xor(v, 8);
        rs[r] = rsqrtf(v * (1.f / 64.f) + LEPS);
    }

    _Float16* wb = (_Float16*)sraw + (size_t)wid * 2304;   // [16][72] f16 view
    #pragma unroll
    for (int ob = 0; ob < 4; ob++) {
        const int col = ob * 16 + fl;
        const float gg = scst[192 + col], bb = scst[256 + col];
        #pragma unroll
        for (int r = 0; r < 4; r++) {
            const float xn = (h[ob][r] - mu[r]) * rs[r] * gg + bb;
            wb[(gq * 4 + r) * 72 + col] = (_Float16)xn;
        }
    }
    __threadfence_block();

    if (!FUSE) {
        const int rr = lane >> 2, cg = lane & 3;
        const half8v o0 = *(const half8v*)(wb + rr * 72 + cg * 16);
        const half8v o1 = *(const half8v*)(wb + rr * 72 + cg * 16 + 8);
        *(half8v*)(xout + (R + rr) * HDIM + cg * 16) = o0;
        *(half8v*)(xout + (R + rr) * HDIM + cg * 16 + 8) = o1;
    } else {
        const half8v FA0 = *(const half8v*)(wb + fl * 72 + gq * 8);
        const half8v FA1 = *(const half8v*)(wb + fl * 72 + 32 + gq * 8);
        float fo[4][4];
        #pragma unroll
        for (int ob = 0; ob < 4; ob++) {
            const int col = ob * 16 + fl;
            const half8v FB0 = *(const half8v*)(fcp + col * 64 + gq * 8);
            const half8v FB1 = *(const half8v*)(fcp + col * 64 + 32 + gq * 8);
            f32x4 z = { 0.f, 0.f, 0.f, 0.f };
            z = __builtin_amdgcn_mfma_f32_16x16x32_f16(FA0, FB0, z, 0, 0, 0);
            z = __builtin_amdgcn_mfma_f32_16x16x32_f16(FA1, FB1, z, 0, 0, 0);
            const float fb = fcb[col];
            #pragma unroll
            for (int r = 0; r < 4; r++) fo[ob][r] = z[r] + fb;
        }
        __threadfence_block();
        float* fb32 = (float*)((char*)sraw + (size_t)wid * 4608);  // [16][68] f32 view
        #pragma unroll
        for (int ob = 0; ob < 4; ob++) {
            const int col = ob * 16 + fl;
            #pragma unroll
            for (int r = 0; r < 4; r++) fb32[(gq * 4 + r) * 68 + col] = fo[ob][r];
        }
        __threadfence_block();
        #pragma unroll
        for (int rr = 0; rr < 16; rr++)
            fout[(R + rr) * HDIM + lane] = fb32[rr * 68 + lane];
    }
}

extern "C" void kernel_launch(void* const* d_in, const int* in_sizes, int n_in,
                              void* d_out, int out_size, void* d_ws, size_t ws_size,
                              hipStream_t stream) {
    const float* x         = (const float*)d_in[0];
    const int*   ei        = (const int*)d_in[1];
    const float* edge_attr = (const float*)d_in[2];
    const int*   node_type = (const int*)d_in[3];
    const int*   edge_type = (const int*)d_in[4];
    const float* Wn        = (const float*)d_in[5];
    const float* bn        = (const float*)d_in[6];
    const float* Wm        = (const float*)d_in[7];
    const float* bm        = (const float*)d_in[8];
    const float* emb       = (const float*)d_in[9];
    const float* ln_g      = (const float*)d_in[10];
    const float* ln_b      = (const float*)d_in[11];
    const float* fc_w      = (const float*)d_in[12];
    const float* fc_b      = (const float*)d_in[13];
    float* out = (float*)d_out;

    char* W = (char*)d_ws;
    int2*      ew0  = (int2*)W;                               // 12.8e6 B
    int2*      ew1  = (int2*)(W + 12800000);                  // 12.8e6 B
    char*      reg  = W + 25600000;
    float*     w0   = (float*)reg;                            // 6.4e6 B
    float*     w1   = (float*)(reg + 6410000);                // 6.4e6 B
    _Float16*  aggr = (_Float16*)reg;                         // reuses region after build
    char*      p2   = reg + 12820000;
    _Float16*  xs   = (_Float16*)p2;                          // 12.8e6 B
    _Float16*  x1s  = (_Float16*)(p2 + 12800000);             // 12.8e6 B
    char*      p3   = p2 + 25600000;
    _Float16*  Wp   = (_Float16*)p3;                          // 49152 B
    _Float16*  fcp  = (_Float16*)(p3 + 49152);                // 8192 B
    int*       deg  = (int*)(p3 + 49152 + 8192);
    int*       off  = deg + NN;                               // NN+1
    int*       curs = off + NN + 16;                          // NN
    int*       bsum = curs + NN;                              // 128
    int*       boff = bsum + 128;                             // 128

    prep_kernel<<<112, 256, 0, stream>>>(Wn, fc_w, Wp, fcp);
    hipMemsetAsync(deg, 0, NN * sizeof(int), stream);
    edge_weights_kernel<<<NE / 256, 256, 0, stream>>>(edge_attr, ei, edge_type,
                                                      Wm, bm, emb, w0, w1, deg);
    // parallel scan (3 tiny kernels)
    partial_kernel<<<NBLK, 256, 0, stream>>>(deg, bsum);
    bscan_kernel<<<1, 128, 0, stream>>>(bsum, boff);
    offsets_kernel<<<NBLK, 256, 0, stream>>>(deg, boff, off, curs);

    xcvt_kernel<<<6250, 256, 0, stream>>>(x, xs);
    build_kernel<<<NE / 256, 256, 0, stream>>>(ei, w0, w1, curs, ew0, ew1);

    // layer 0
    gather_kernel<<<NN / 8, 512, 0, stream>>>(xs, ew0, off, aggr);
    update_kernel<0><<<(NTILES + 3) / 4, 256, 0, stream>>>(aggr, node_type,
        Wp, bn, ln_g, ln_b, fcp, fc_b, x1s, nullptr);
    // layer 1 (+FC)
    gather_kernel<<<NN / 8, 512, 0, stream>>>(x1s, ew1, off, aggr);
    update_kernel<1><<<(NTILES + 3) / 4, 256, 0, stream>>>(aggr, node_type,
        Wp + 3 * 4096, bn + NTT * HDIM, ln_g + HDIM, ln_b + HDIM, fcp, fc_b, nullptr, out);
}

// Round 5
// 404.833 us; speedup vs baseline: 2.8919x; 1.0260x over previous
//
#include <hip/hip_runtime.h>

#define NN 100000
#define NE 1600000
#define HDIM 64
#define EDIM 32
#define NTT 3
#define ETT 4
#define NTILES 6250
#define LEPS 1e-5f
#define CHUNK 1024
#define NBLK 98   // ceil(NN / CHUNK)

typedef _Float16 half4v __attribute__((ext_vector_type(4)));
typedef _Float16 half8v __attribute__((ext_vector_type(8)));
typedef float f32x4 __attribute__((ext_vector_type(4)));

// ---- K0: prep weights: Wp[l][t][o][d] = f16(Wn[l][t][d][o]); fcp = f16(fc_w) ----
__global__ void prep_kernel(const float* __restrict__ Wn, const float* __restrict__ fc_w,
                            _Float16* __restrict__ Wp, _Float16* __restrict__ fcp) {
    const int i = blockIdx.x * blockDim.x + threadIdx.x;
    if (i < 6 * HDIM * HDIM) {
        const int lt = i >> 12;          // [l*3+t]
        const int o = (i >> 6) & 63;
        const int d = i & 63;
        Wp[i] = (_Float16)Wn[((size_t)lt * 64 + d) * 64 + o];
    } else if (i < 6 * HDIM * HDIM + HDIM * HDIM) {
        const int j = i - 6 * HDIM * HDIM;
        fcp[j] = (_Float16)fc_w[j];      // fc_w already [o][h]
    }
}

// ---- K1: edge gates for both layers + degree histogram ----
__global__ void edge_weights_kernel(const float* __restrict__ edge_attr,
                                    const int* __restrict__ ei,
                                    const int* __restrict__ edge_type,
                                    const float* __restrict__ Wm,
                                    const float* __restrict__ bm,
                                    const float* __restrict__ emb,
                                    float* __restrict__ w0,
                                    float* __restrict__ w1,
                                    int* __restrict__ deg) {
    __shared__ float sWm[2 * ETT * EDIM];
    __shared__ float sc[2 * ETT];
    const int tid = threadIdx.x;
    if (tid < 2 * ETT * EDIM) sWm[tid] = Wm[tid];
    __syncthreads();
    if (tid < 2 * ETT) {
        float c = bm[tid];
        #pragma unroll
        for (int k = 0; k < EDIM; k++) c += emb[tid * EDIM + k] * sWm[tid * EDIM + k];
        sc[tid] = c;
    }
    __syncthreads();
    const int e = blockIdx.x * blockDim.x + tid;
    if (e >= NE) return;
    const int et = edge_type[e];
    const float4* ea = (const float4*)(edge_attr + (size_t)e * EDIM);
    const float4* m0 = (const float4*)(sWm + et * EDIM);
    const float4* m1 = (const float4*)(sWm + (ETT + et) * EDIM);
    float d0 = sc[et];
    float d1 = sc[ETT + et];
    #pragma unroll
    for (int k = 0; k < EDIM / 4; k++) {
        const float4 v = ea[k];
        const float4 a = m0[k];
        const float4 b = m1[k];
        d0 += v.x * a.x + v.y * a.y + v.z * a.z + v.w * a.w;
        d1 += v.x * b.x + v.y * b.y + v.z * b.z + v.w * b.w;
    }
    w0[e] = fmaxf(d0, 0.f) + log1pf(expf(-fabsf(d0)));
    w1[e] = fmaxf(d1, 0.f) + log1pf(expf(-fabsf(d1)));
    atomicAdd(&deg[ei[NE + e]], 1);
}

// ---- K2a: per-chunk sums ----
__global__ __launch_bounds__(256) void partial_kernel(const int* __restrict__ deg,
                                                      int* __restrict__ bsum) {
    __shared__ int red[256];
    const int b = blockIdx.x, t = threadIdx.x;
    const int base = b * CHUNK + t * 4;
    int s = 0;
    #pragma unroll
    for (int k = 0; k < 4; k++) { const int i = base + k; if (i < NN) s += deg[i]; }
    red[t] = s;
    __syncthreads();
    for (int d = 128; d > 0; d >>= 1) {
        if (t < d) red[t] += red[t + d];
        __syncthreads();
    }
    if (t == 0) bsum[b] = red[0];
}

// ---- K2b: exclusive scan of the 98 chunk sums (1 tiny block) ----
__global__ void bscan_kernel(const int* __restrict__ bsum, int* __restrict__ boff) {
    __shared__ int v[128];
    const int t = threadIdx.x;
    v[t] = (t < NBLK) ? bsum[t] : 0;
    __syncthreads();
    for (int d = 1; d < 128; d <<= 1) {
        const int x = (t >= d) ? v[t - d] : 0;
        __syncthreads();
        v[t] += x;
        __syncthreads();
    }
    boff[t] = (t == 0) ? 0 : v[t - 1];
}

// ---- K2c: intra-chunk exclusive scan -> off, cursor ----
__global__ __launch_bounds__(256) void offsets_kernel(const int* __restrict__ deg,
                                                      const int* __restrict__ boff,
                                                      int* __restrict__ off,
                                                      int* __restrict__ cursor) {
    __shared__ int red[256];
    const int b = blockIdx.x, t = threadIdx.x;
    const int base = b * CHUNK + t * 4;
    int d4[4];
    #pragma unroll
    for (int k = 0; k < 4; k++) d4[k] = (base + k < NN) ? deg[base + k] : 0;
    const int s = d4[0] + d4[1] + d4[2] + d4[3];
    red[t] = s;
    __syncthreads();
    for (int d = 1; d < 256; d <<= 1) {
        const int x = (t >= d) ? red[t - d] : 0;
        __syncthreads();
        red[t] += x;
        __syncthreads();
    }
    int run = boff[b] + ((t == 0) ? 0 : red[t - 1]);
    #pragma unroll
    for (int k = 0; k < 4; k++) {
        if (base + k < NN) {
            off[base + k] = run;
            cursor[base + k] = run;
            run += d4[k];
        }
    }
    if (b == NBLK - 1 && t == 255) off[NN] = NE;
}

// ---- K3: x -> fp16 ----
__global__ void xcvt_kernel(const float* __restrict__ x, _Float16* __restrict__ xs) {
    const int i = blockIdx.x * blockDim.x + threadIdx.x;
    const float4 v = ((const float4*)x)[i];
    half4v o = { (_Float16)v.x, (_Float16)v.y, (_Float16)v.z, (_Float16)v.w };
    ((half4v*)xs)[i] = o;
}

// ---- K4: place edges into CSR order, packed {w, src} ----
__global__ void build_kernel(const int* __restrict__ ei,
                             const float* __restrict__ w0,
                             const float* __restrict__ w1,
                             int* __restrict__ cursor,
                             int2* __restrict__ ew0,
                             int2* __restrict__ ew1) {
    const int e = blockIdx.x * blockDim.x + threadIdx.x;
    if (e >= NE) return;
    const int t = ei[NE + e];
    const int s = ei[e];
    const int pos = atomicAdd(&cursor[t], 1);
    ew0[pos] = make_int2(__float_as_int(w0[e]), s);
    ew1[pos] = make_int2(__float_as_int(w1[e]), s);
}

// ---- K5/K7: gather: aggr[p] = sum w*x[src] - (sum w)*x[p] ----
__global__ __launch_bounds__(512) void gather_kernel(const _Float16* __restrict__ xs,
                                                     const int2* __restrict__ ew,
                                                     const int* __restrict__ off,
                                                     _Float16* __restrict__ aggr) {
    const int lane = threadIdx.x & 63;
    const int wid = threadIdx.x >> 6;
    const int p = blockIdx.x * 8 + wid;
    const int g = lane >> 4;
    const int fl = lane & 15;
    const int lo = off[p], hi = off[p + 1];
    float a0 = 0.f, a1 = 0.f, a2 = 0.f, a3 = 0.f, sw = 0.f;
    for (int base = lo; base < hi; base += 4) {
        const int i = base + g;
        if (i < hi) {
            const int2 e = ew[i];
            const float w = __int_as_float(e.x);
            const half4v xv = *(const half4v*)(xs + (size_t)e.y * HDIM + fl * 4);
            a0 += w * (float)xv[0];
            a1 += w * (float)xv[1];
            a2 += w * (float)xv[2];
            a3 += w * (float)xv[3];
            sw += w;
        }
    }
    a0 += __shfl_xor(a0, 16); a1 += __shfl_xor(a1, 16);
    a2 += __shfl_xor(a2, 16); a3 += __shfl_xor(a3, 16);
    sw += __shfl_xor(sw, 16);
    a0 += __shfl_xor(a0, 32); a1 += __shfl_xor(a1, 32);
    a2 += __shfl_xor(a2, 32); a3 += __shfl_xor(a3, 32);
    sw += __shfl_xor(sw, 32);
    const half4v xt = *(const half4v*)(xs + (size_t)p * HDIM + fl * 4);
    a0 -= sw * (float)xt[0];
    a1 -= sw * (float)xt[1];
    a2 -= sw * (float)xt[2];
    a3 -= sw * (float)xt[3];
    if (g == 0) {
        half4v o = { (_Float16)a0, (_Float16)a1, (_Float16)a2, (_Float16)a3 };
        *(half4v*)(aggr + (size_t)p * HDIM + fl * 4) = o;
    }
}

// ---- K6/K8: update: h = relu(aggr @ Wn[nt] + bn[nt]); LN; [FC] ----
template<int FUSE>
__global__ __launch_bounds__(256) void update_kernel(const _Float16* __restrict__ aggr,
                                                     const int* __restrict__ ntype,
                                                     const _Float16* __restrict__ Wp,
                                                     const float* __restrict__ bnp,
                                                     const float* __restrict__ lng,
                                                     const float* __restrict__ lnb,
                                                     const _Float16* __restrict__ fcp,
                                                     const float* __restrict__ fcb,
                                                     _Float16* __restrict__ xout,
                                                     float* __restrict__ fout) {
    __shared__ float scst[320];
    __shared__ f32x4 sraw[4 * 4608 / 16];
    for (int i = threadIdx.x; i < 320; i += 256)
        scst[i] = (i < 192) ? bnp[i] : ((i < 256) ? lng[i - 192] : lnb[i - 256]);
    __syncthreads();

    const int wid = threadIdx.x >> 6;
    const int lane = threadIdx.x & 63;
    const int tile = blockIdx.x * 4 + wid;
    if (tile >= NTILES) return;
    const int fl = lane & 15;
    const int gq = lane >> 4;
    const size_t R = (size_t)tile * 16;

    const half8v A0 = *(const half8v*)(aggr + (R + fl) * HDIM + gq * 8);
    const half8v A1 = *(const half8v*)(aggr + (R + fl) * HDIM + 32 + gq * 8);
    int nt[4];
    #pragma unroll
    for (int r = 0; r < 4; r++) nt[r] = ntype[R + gq * 4 + r];

    float h[4][4];
    #pragma unroll
    for (int ob = 0; ob < 4; ob++) {
        const int col = ob * 16 + fl;
        f32x4 c[3];
        #pragma unroll
        for (int t = 0; t < 3; t++) {
            const half8v B0 = *(const half8v*)(Wp + t * 4096 + col * 64 + gq * 8);
            const half8v B1 = *(const half8v*)(Wp + t * 4096 + col * 64 + 32 + gq * 8);
            f32x4 z = { 0.f, 0.f, 0.f, 0.f };
            z = __builtin_amdgcn_mfma_f32_16x16x32_f16(A0, B0, z, 0, 0, 0);
            z = __builtin_amdgcn_mfma_f32_16x16x32_f16(A1, B1, z, 0, 0, 0);
            c[t] = z;
        }
        #pragma unroll
        for (int r = 0; r < 4; r++) {
            float v = (nt[r] == 0) ? c[0][r] : ((nt[r] == 1) ? c[1][r] : c[2][r]);
            v += scst[nt[r] * 64 + col];
            h[ob][r] = fmaxf(v, 0.f);
        }
    }

    float mu[4], rs[4];
    #pragma unroll
    for (int r = 0; r < 4; r++) {
        float m = h[0][r] + h[1][r] + h[2][r] + h[3][r];
        m += __shfl_xor(m, 1); m += __shfl_xor(m, 2);
        m += __shfl_xor(m, 4); m += __shfl_xor(m, 8);
        mu[r] = m * (1.f / 64.f);
        const float d0 = h[0][r] - mu[r], d1 = h[1][r] - mu[r];
        const float d2 = h[2][r] - mu[r], d3 = h[3][r] - mu[r];
        float v = d0 * d0 + d1 * d1 + d2 * d2 + d3 * d3;
        v += __shfl_xor(v, 1); v += __shfl_xor(v, 2);
        v += __shfl_xor(v, 4); v += __shfl_xor(v, 8);
        rs[r] = rsqrtf(v * (1.f / 64.f) + LEPS);
    }

    _Float16* wb = (_Float16*)sraw + (size_t)wid * 2304;   // [16][72] f16 view
    #pragma unroll
    for (int ob = 0; ob < 4; ob++) {
        const int col = ob * 16 + fl;
        const float gg = scst[192 + col], bb = scst[256 + col];
        #pragma unroll
        for (int r = 0; r < 4; r++) {
            const float xn = (h[ob][r] - mu[r]) * rs[r] * gg + bb;
            wb[(gq * 4 + r) * 72 + col] = (_Float16)xn;
        }
    }
    __threadfence_block();

    if (!FUSE) {
        const int rr = lane >> 2, cg = lane & 3;
        const half8v o0 = *(const half8v*)(wb + rr * 72 + cg * 16);
        const half8v o1 = *(const half8v*)(wb + rr * 72 + cg * 16 + 8);
        *(half8v*)(xout + (R + rr) * HDIM + cg * 16) = o0;
        *(half8v*)(xout + (R + rr) * HDIM + cg * 16 + 8) = o1;
    } else {
        const half8v FA0 = *(const half8v*)(wb + fl * 72 + gq * 8);
        const half8v FA1 = *(const half8v*)(wb + fl * 72 + 32 + gq * 8);
        float fo[4][4];
        #pragma unroll
        for (int ob = 0; ob < 4; ob++) {
            const int col = ob * 16 + fl;
            const half8v FB0 = *(const half8v*)(fcp + col * 64 + gq * 8);
            const half8v FB1 = *(const half8v*)(fcp + col * 64 + 32 + gq * 8);
            f32x4 z = { 0.f, 0.f, 0.f, 0.f };
            z = __builtin_amdgcn_mfma_f32_16x16x32_f16(FA0, FB0, z, 0, 0, 0);
            z = __builtin_amdgcn_mfma_f32_16x16x32_f16(FA1, FB1, z, 0, 0, 0);
            const float fb = fcb[col];
            #pragma unroll
            for (int r = 0; r < 4; r++) fo[ob][r] = z[r] + fb;
        }
        __threadfence_block();
        float* fb32 = (float*)((char*)sraw + (size_t)wid * 4608);  // [16][68] f32 view
        #pragma unroll
        for (int ob = 0; ob < 4; ob++) {
            const int col = ob * 16 + fl;
            #pragma unroll
            for (int r = 0; r < 4; r++) fb32[(gq * 4 + r) * 68 + col] = fo[ob][r];
        }
        __threadfence_block();
        #pragma unroll
        for (int rr = 0; rr < 16; rr++)
            fout[(R + rr) * HDIM + lane] = fb32[rr * 68 + lane];
    }
}

extern "C" void kernel_launch(void* const* d_in, const int* in_sizes, int n_in,
                              void* d_out, int out_size, void* d_ws, size_t ws_size,
                              hipStream_t stream) {
    const float* x         = (const float*)d_in[0];
    const int*   ei        = (const int*)d_in[1];
    const float* edge_attr = (const float*)d_in[2];
    const int*   node_type = (const int*)d_in[3];
    const int*   edge_type = (const int*)d_in[4];
    const float* Wn        = (const float*)d_in[5];
    const float* bn        = (const float*)d_in[6];
    const float* Wm        = (const float*)d_in[7];
    const float* bm        = (const float*)d_in[8];
    const float* emb       = (const float*)d_in[9];
    const float* ln_g      = (const float*)d_in[10];
    const float* ln_b      = (const float*)d_in[11];
    const float* fc_w      = (const float*)d_in[12];
    const float* fc_b      = (const float*)d_in[13];
    float* out = (float*)d_out;

    char* W = (char*)d_ws;
    int2*      ew0  = (int2*)W;                               // 12.8e6 B
    int2*      ew1  = (int2*)(W + 12800000);                  // 12.8e6 B
    char*      reg  = W + 25600000;
    float*     w0   = (float*)reg;                            // 6.4e6 B
    float*     w1   = (float*)(reg + 6410000);                // 6.4e6 B
    _Float16*  aggr = (_Float16*)reg;                         // reuses region after build
    char*      p2   = reg + 12820000;
    _Float16*  xs   = (_Float16*)p2;                          // 12.8e6 B
    _Float16*  x1s  = (_Float16*)(p2 + 12800000);             // 12.8e6 B
    char*      p3   = p2 + 25600000;
    _Float16*  Wp   = (_Float16*)p3;                          // 49152 B
    _Float16*  fcp  = (_Float16*)(p3 + 49152);                // 8192 B
    int*       deg  = (int*)(p3 + 49152 + 8192);
    int*       off  = deg + NN;                               // NN+1
    int*       curs = off + NN + 16;                          // NN
    int*       bsum = curs + NN;                              // 128
    int*       boff = bsum + 128;                             // 128

    prep_kernel<<<112, 256, 0, stream>>>(Wn, fc_w, Wp, fcp);
    hipMemsetAsync(deg, 0, NN * sizeof(int), stream);
    edge_weights_kernel<<<NE / 256, 256, 0, stream>>>(edge_attr, ei, edge_type,
                                                      Wm, bm, emb, w0, w1, deg);
    // parallel scan (3 tiny kernels)
    partial_kernel<<<NBLK, 256, 0, stream>>>(deg, bsum);
    bscan_kernel<<<1, 128, 0, stream>>>(bsum, boff);
    offsets_kernel<<<NBLK, 256, 0, stream>>>(deg, boff, off, curs);

    xcvt_kernel<<<6250, 256, 0, stream>>>(x, xs);
    build_kernel<<<NE / 256, 256, 0, stream>>>(ei, w0, w1, curs, ew0, ew1);

    // layer 0
    gather_kernel<<<NN / 8, 512, 0, stream>>>(xs, ew0, off, aggr);
    update_kernel<0><<<(NTILES + 3) / 4, 256, 0, stream>>>(aggr, node_type,
        Wp, bn, ln_g, ln_b, fcp, fc_b, x1s, nullptr);
    // layer 1 (+FC)
    gather_kernel<<<NN / 8, 512, 0, stream>>>(x1s, ew1, off, aggr);
    update_kernel<1><<<(NTILES + 3) / 4, 256, 0, stream>>>(aggr, node_type,
        Wp + 3 * 4096, bn + NTT * HDIM, ln_g + HDIM, ln_b + HDIM, fcp, fc_b, nullptr, out);
}